// Round 8
// baseline (342.698 us; speedup 1.0000x reference)
//
#include <hip/hip_runtime.h>

typedef __bf16 bf16_t;
typedef bf16_t bf16x8 __attribute__((ext_vector_type(8)));
typedef bf16_t bf16x4 __attribute__((ext_vector_type(4)));
typedef float f32x4 __attribute__((ext_vector_type(4)));

#define N_PTS 8192
#define C_DIM 256
#define K_NN 16
#define Q_BLK 16  // queries per knn block

// ---------------------------------------------------------------- prep: cast feats to bf16
__global__ __launch_bounds__(256) void cast_feats_kernel(const float* __restrict__ f,
                                                         bf16_t* __restrict__ fb) {
    int i = (blockIdx.x * 256 + threadIdx.x) * 4;
    float4 v = *(const float4*)(f + i);
    bf16x4 o;
    o[0] = (bf16_t)v.x; o[1] = (bf16_t)v.y; o[2] = (bf16_t)v.z; o[3] = (bf16_t)v.w;
    *(bf16x4*)(fb + i) = o;
}

// ---------------------------------------------------------------- prep: weights -> MFMA B-fragment-major bf16
// Wt[((t*8+kb)*512) + lm*32 + q*8 + e] = W[k = kb*32+q*8+e][n = t*16+lm].
__global__ __launch_bounds__(256) void prep_weights_kernel(
    const float* __restrict__ w0, const float* __restrict__ w1,
    const float* __restrict__ w2, const float* __restrict__ w3,
    const float* __restrict__ w4, bf16_t* __restrict__ wt_base) {
    int m = blockIdx.y;
    const float* src = (m == 0) ? w0 : (m == 1) ? w1 : (m == 2) ? w2 : (m == 3) ? w3 : w4;
    bf16_t* dst = wt_base + m * (C_DIM * C_DIM);
#pragma unroll
    for (int i = 0; i < 4; ++i) {
        int o = blockIdx.x * 1024 + i * 256 + threadIdx.x;
        int tkb = o >> 9;           // t*8 + kb
        int rem = o & 511;
        int lm = rem >> 5;
        int r = rem & 31;           // q*8 + e
        int k = (tkb & 7) * 32 + r;
        int n = (tkb >> 3) * 16 + lm;
        dst[o] = (bf16_t)src[k * C_DIM + n];
    }
}

// ---------------------------------------------------------------- KNN: 16 queries per 256-thread block
// d2 bits emulate the numpy reference exactly (validated rounds 3-7):
//   sq  = (fl(x^2)+fl(y^2))+fl(z^2); dot = fma(z,z',fma(y,y',fl(x*x')));
//   d2  = fl(fl(sq_i+sq_j) - fl(2*dot))
// One coord stream serves 16 queries. Pass 1: per-thread mins -> 16 disjoint
// group-mins (512 pts each) -> tau[q] >= 16th-NN dist (provable). Pass 2: reload
// (L1-hot), recompute identical d2 bits, compact survivors per query. Selection:
// wave w handles queries w*4..w*4+3 via 16 wave-argmin rounds over unique
// (ordered_d2, idx) u64 keys. Ties -> lower index (stable top_k).
__global__ __launch_bounds__(256) void knn_kernel(const float* __restrict__ coords,
                                                  int* __restrict__ idx_out) {
    const int tid = threadIdx.x;
    const int wave = tid >> 6, lane = tid & 63;
    const int n0 = blockIdx.x * Q_BLK;
    __shared__ float red16[Q_BLK][16];
    __shared__ unsigned long long cand[Q_BLK][256];
    __shared__ int cnt[Q_BLK];

    if (tid < Q_BLK) cnt[tid] = 0;

    // load 16 query coords (48 floats, broadcast across lanes)
    float qx[Q_BLK], qy[Q_BLK], qz[Q_BLK], sqi[Q_BLK];
    {
        float qbuf[48];
#pragma unroll
        for (int v = 0; v < 12; ++v)
            *(float4*)(qbuf + v * 4) = *(const float4*)(coords + n0 * 3 + v * 4);
#pragma unroll
        for (int q = 0; q < Q_BLK; ++q) {
            qx[q] = qbuf[3 * q + 0]; qy[q] = qbuf[3 * q + 1]; qz[q] = qbuf[3 * q + 2];
            sqi[q] = __fadd_rn(__fadd_rn(__fmul_rn(qx[q], qx[q]), __fmul_rn(qy[q], qy[q])),
                               __fmul_rn(qz[q], qz[q]));
        }
    }

    const float INF = __int_as_float(0x7f800000);
    const float* cp = coords + tid * 96;

    // ---- pass 1: per-thread min per query over owned 32 points
    float lmin[Q_BLK];
#pragma unroll
    for (int q = 0; q < Q_BLK; ++q) lmin[q] = INF;
#pragma unroll
    for (int c = 0; c < 4; ++c) {
        float buf[24];
#pragma unroll
        for (int v = 0; v < 6; ++v)
            *(float4*)(buf + v * 4) = *(const float4*)(cp + c * 24 + v * 4);
#pragma unroll
        for (int p = 0; p < 8; ++p) {
            float x = buf[3 * p + 0], y = buf[3 * p + 1], z = buf[3 * p + 2];
            float sqj = __fadd_rn(__fadd_rn(__fmul_rn(x, x), __fmul_rn(y, y)),
                                  __fmul_rn(z, z));
#pragma unroll
            for (int q = 0; q < Q_BLK; ++q) {
                float dot = __fmaf_rn(z, qz[q], __fmaf_rn(y, qy[q], __fmul_rn(x, qx[q])));
                float d2 = __fsub_rn(__fadd_rn(sqi[q], sqj), __fmul_rn(2.0f, dot));
                lmin[q] = fminf(lmin[q], d2);
            }
        }
    }

    // ---- 16 disjoint group-mins (16 threads = 512 points each) -> tau per query
#pragma unroll
    for (int q = 0; q < Q_BLK; ++q) {
        float g = lmin[q];
        g = fminf(g, __shfl_xor(g, 1));
        g = fminf(g, __shfl_xor(g, 2));
        g = fminf(g, __shfl_xor(g, 4));
        g = fminf(g, __shfl_xor(g, 8));
        if ((lane & 15) == 0) red16[q][wave * 4 + (lane >> 4)] = g;
    }
    __syncthreads();

    float tau[Q_BLK];
#pragma unroll
    for (int q = 0; q < Q_BLK; ++q) {
        float t = red16[q][0];
#pragma unroll
        for (int i = 1; i < 16; ++i) t = fmaxf(t, red16[q][i]);
        tau[q] = t;
    }

    // ---- pass 2: reload (L1-hot), recompute identical d2 bits, compact survivors
#pragma unroll
    for (int c = 0; c < 4; ++c) {
        float buf[24];
#pragma unroll
        for (int v = 0; v < 6; ++v)
            *(float4*)(buf + v * 4) = *(const float4*)(cp + c * 24 + v * 4);
#pragma unroll
        for (int p = 0; p < 8; ++p) {
            float x = buf[3 * p + 0], y = buf[3 * p + 1], z = buf[3 * p + 2];
            float sqj = __fadd_rn(__fadd_rn(__fmul_rn(x, x), __fmul_rn(y, y)),
                                  __fmul_rn(z, z));
            int j = tid * 32 + c * 8 + p;
#pragma unroll
            for (int q = 0; q < Q_BLK; ++q) {
                float dot = __fmaf_rn(z, qz[q], __fmaf_rn(y, qy[q], __fmul_rn(x, qx[q])));
                float d2 = __fsub_rn(__fadd_rn(sqi[q], sqj), __fmul_rn(2.0f, dot));
                if (d2 <= tau[q]) {
                    unsigned u = __float_as_uint(d2);
                    u = (u & 0x80000000u) ? ~u : (u | 0x80000000u);
                    int slot = atomicAdd(&cnt[q], 1);
                    if (slot < 256)
                        cand[q][slot] = (((unsigned long long)u) << 32) | (unsigned)j;
                }
            }
        }
    }
    __syncthreads();

    // ---- selection: wave w -> queries w*4+i, 16 wave-argmin rounds each
#pragma unroll 1
    for (int i = 0; i < 4; ++i) {
        const int qq = wave * 4 + i;
        int m = cnt[qq]; if (m > 256) m = 256;
        unsigned long long k0 = ~0ull, k1 = ~0ull, k2 = ~0ull, k3 = ~0ull;
        if (lane < m) k0 = cand[qq][lane];
        if (lane + 64 < m) k1 = cand[qq][lane + 64];
        if (lane + 128 < m) k2 = cand[qq][lane + 128];
        if (lane + 192 < m) k3 = cand[qq][lane + 192];
        unsigned long long lm2 = k0; int li = 0;
        if (k1 < lm2) { lm2 = k1; li = 1; }
        if (k2 < lm2) { lm2 = k2; li = 2; }
        if (k3 < lm2) { lm2 = k3; li = 3; }
        int keep = 0;
#pragma unroll 1
        for (int r = 0; r < 16; ++r) {
            unsigned long long w = lm2;
#pragma unroll
            for (int off = 1; off < 64; off <<= 1) {
                unsigned long long o = __shfl_xor(w, off);
                w = (o < w) ? o : w;
            }
            if (lane == r) keep = (int)(unsigned)(w & 0xffffffffull);
            if (lm2 == w) {  // unique winner: retire slot, recompute local min
                if (li == 0) k0 = ~0ull;
                else if (li == 1) k1 = ~0ull;
                else if (li == 2) k2 = ~0ull;
                else k3 = ~0ull;
                lm2 = k0; li = 0;
                if (k1 < lm2) { lm2 = k1; li = 1; }
                if (k2 < lm2) { lm2 = k2; li = 2; }
                if (k3 < lm2) { lm2 = k3; li = 3; }
            }
        }
        if (lane < 16) idx_out[(n0 + qq) * K_NN + lane] = keep;
    }
}

// ---------------------------------------------------------------- proj: T/P/G = feats@{theta,phi,g}+b
// B-reuse split: wave owns 4 col-tiles (B preloaded in regs), loops 4 row-tiles.
__global__ __launch_bounds__(256, 2) void proj_kernel(
    const bf16_t* __restrict__ fb, const bf16_t* __restrict__ wt_base,
    const float* __restrict__ tb, const float* __restrict__ pb, const float* __restrict__ gb,
    float* __restrict__ T, bf16_t* __restrict__ Pb, bf16_t* __restrict__ Gb) {
    const int sel = blockIdx.y;
    const bf16_t* Wt = wt_base + sel * (C_DIM * C_DIM);
    const float* bias = (sel == 0) ? tb : (sel == 1) ? pb : gb;
    const int wave = threadIdx.x >> 6, lane = threadIdx.x & 63;
    const int q = lane >> 4, lm = lane & 15;
    const int m0 = blockIdx.x * 64;

    bf16x8 bfr[4][8];
#pragma unroll
    for (int ti = 0; ti < 4; ++ti)
#pragma unroll
        for (int kb = 0; kb < 8; ++kb)
            bfr[ti][kb] = *(const bf16x8*)(Wt + (((wave * 4 + ti) * 8 + kb) << 9) + lm * 32 + q * 8);

    float bv[4];
#pragma unroll
    for (int ti = 0; ti < 4; ++ti) bv[ti] = bias[(wave * 4 + ti) * 16 + lm];

#pragma unroll
    for (int p = 0; p < 4; ++p) {
        const bf16_t* arow = fb + (m0 + p * 16 + lm) * C_DIM + q * 8;
        bf16x8 a[8];
#pragma unroll
        for (int kb = 0; kb < 8; ++kb) a[kb] = *(const bf16x8*)(arow + kb * 32);
        f32x4 acc[4];
#pragma unroll
        for (int ti = 0; ti < 4; ++ti) acc[ti] = (f32x4){0.f, 0.f, 0.f, 0.f};
#pragma unroll
        for (int ti = 0; ti < 4; ++ti)
#pragma unroll
            for (int kb = 0; kb < 8; ++kb)
                acc[ti] = __builtin_amdgcn_mfma_f32_16x16x32_bf16(a[kb], bfr[ti][kb], acc[ti], 0, 0, 0);

#pragma unroll
        for (int ti = 0; ti < 4; ++ti) {
            int c = (wave * 4 + ti) * 16 + lm;
#pragma unroll
            for (int r = 0; r < 4; ++r) {
                float v = acc[ti][r] + bv[ti];
                int off = (m0 + p * 16 + q * 4 + r) * C_DIM + c;
                if (sel == 0) T[off] = v;
                else if (sel == 1) Pb[off] = (bf16_t)v;
                else Gb[off] = (bf16_t)v;
            }
        }
    }
}

// ---------------------------------------------------------------- pe1 + pe2 GEMM + softmax + weighted G-sum (fused)
#define HPAD 264  // 256 + 8 bf16 pad
#define P_BLK 8
#define HROWS (P_BLK * 16)
__global__ __launch_bounds__(256, 2) void pe2_fused_kernel(
    const float* __restrict__ coords, const int* __restrict__ idx,
    const float* __restrict__ T, const bf16_t* __restrict__ Pb, const bf16_t* __restrict__ Gb,
    const float* __restrict__ w1, const float* __restrict__ b1, const float* __restrict__ b2,
    const bf16_t* __restrict__ Wt2, bf16_t* __restrict__ yb) {
    __shared__ __align__(16) bf16_t h_lds[HROWS * HPAD];
    __shared__ float dxyz[HROWS][3];
    __shared__ int idxl[HROWS];
    const int tid = threadIdx.x;
    const int p0 = blockIdx.x * P_BLK;
    const int wave = tid >> 6, lane = tid & 63;
    const int q = lane >> 4, lm = lane & 15;

    bf16x8 bfr[4][8];
#pragma unroll
    for (int ti = 0; ti < 4; ++ti)
#pragma unroll
        for (int kb = 0; kb < 8; ++kb)
            bfr[ti][kb] = *(const bf16x8*)(Wt2 + (((wave * 4 + ti) * 8 + kb) << 9) + lm * 32 + q * 8);
    float b2c[4];
#pragma unroll
    for (int ti = 0; ti < 4; ++ti) b2c[ti] = b2[(wave * 4 + ti) * 16 + lm];

    if (tid < HROWS) {
        int n = p0 + (tid >> 4);
        int j = idx[n * K_NN + (tid & 15)];
        idxl[tid] = j;
        dxyz[tid][0] = coords[3 * j + 0] - coords[3 * n + 0];
        dxyz[tid][1] = coords[3 * j + 1] - coords[3 * n + 1];
        dxyz[tid][2] = coords[3 * j + 2] - coords[3 * n + 2];
    }
    __syncthreads();

    {   // pe1: h = relu(delta @ w1 + b1) -> LDS bf16 (thread owns col c = tid)
        int c = tid;
        float wx = w1[c], wy = w1[C_DIM + c], wz = w1[2 * C_DIM + c], bb = b1[c];
#pragma unroll 4
        for (int r = 0; r < HROWS; ++r) {
            float pre = dxyz[r][0] * wx + dxyz[r][1] * wy + dxyz[r][2] * wz + bb;
            h_lds[r * HPAD + c] = (bf16_t)fmaxf(pre, 0.0f);
        }
    }
    __syncthreads();

#pragma unroll 1
    for (int lp = 0; lp < P_BLK; ++lp) {
        const int n = p0 + lp;
        const bf16_t* hrow = h_lds + (lp * 16 + lm) * HPAD + q * 8;
        bf16x8 a[8];
#pragma unroll
        for (int kb = 0; kb < 8; ++kb) a[kb] = *(const bf16x8*)(hrow + kb * 32);
        f32x4 acc[4];
#pragma unroll
        for (int ti = 0; ti < 4; ++ti) acc[ti] = (f32x4){0.f, 0.f, 0.f, 0.f};
#pragma unroll
        for (int ti = 0; ti < 4; ++ti)
#pragma unroll
            for (int kb = 0; kb < 8; ++kb)
                acc[ti] = __builtin_amdgcn_mfma_f32_16x16x32_bf16(a[kb], bfr[ti][kb], acc[ti], 0, 0, 0);

        int jr[4];
#pragma unroll
        for (int r = 0; r < 4; ++r) jr[r] = idxl[lp * 16 + q * 4 + r];

#pragma unroll
        for (int ti = 0; ti < 4; ++ti) {
            int c = (wave * 4 + ti) * 16 + lm;
            float phi[4], gv[4];
#pragma unroll
            for (int r = 0; r < 4; ++r) {
                phi[r] = (float)Pb[jr[r] * C_DIM + c];
                gv[r]  = (float)Gb[jr[r] * C_DIM + c];
            }
            float Tn = T[n * C_DIM + c];
            float df[4];
#pragma unroll
            for (int r = 0; r < 4; ++r) {
                float pe = acc[ti][r] + b2c[ti];
                df[r] = (pe * (Tn - phi[r]) + pe) * 0.0625f;  // /sqrt(256)
            }
            float mx = fmaxf(fmaxf(df[0], df[1]), fmaxf(df[2], df[3]));
            mx = fmaxf(mx, __shfl_xor(mx, 16));
            mx = fmaxf(mx, __shfl_xor(mx, 32));
            float e[4], s = 0.f;
#pragma unroll
            for (int r = 0; r < 4; ++r) { e[r] = __expf(df[r] - mx); s += e[r]; }
            s += __shfl_xor(s, 16);
            s += __shfl_xor(s, 32);
            float inv = 1.0f / s;
            float y = 0.f;
#pragma unroll
            for (int r = 0; r < 4; ++r) y += e[r] * inv * gv[r];
            y += __shfl_xor(y, 16);
            y += __shfl_xor(y, 32);
            if (q == 0) yb[n * C_DIM + c] = (bf16_t)y;
        }
    }
}

// ---------------------------------------------------------------- final: out = y@W_w + W_b + feats
__global__ __launch_bounds__(256, 2) void final_kernel(
    const bf16_t* __restrict__ yb, const bf16_t* __restrict__ Wt,
    const float* __restrict__ Wb, const float* __restrict__ feats,
    float* __restrict__ out) {
    const int wave = threadIdx.x >> 6, lane = threadIdx.x & 63;
    const int q = lane >> 4, lm = lane & 15;
    const int m0 = blockIdx.x * 64;

    bf16x8 bfr[4][8];
#pragma unroll
    for (int ti = 0; ti < 4; ++ti)
#pragma unroll
        for (int kb = 0; kb < 8; ++kb)
            bfr[ti][kb] = *(const bf16x8*)(Wt + (((wave * 4 + ti) * 8 + kb) << 9) + lm * 32 + q * 8);
    float bv[4];
#pragma unroll
    for (int ti = 0; ti < 4; ++ti) bv[ti] = Wb[(wave * 4 + ti) * 16 + lm];

#pragma unroll
    for (int p = 0; p < 4; ++p) {
        const bf16_t* arow = yb + (m0 + p * 16 + lm) * C_DIM + q * 8;
        bf16x8 a[8];
#pragma unroll
        for (int kb = 0; kb < 8; ++kb) a[kb] = *(const bf16x8*)(arow + kb * 32);
        f32x4 acc[4];
#pragma unroll
        for (int ti = 0; ti < 4; ++ti) acc[ti] = (f32x4){0.f, 0.f, 0.f, 0.f};
#pragma unroll
        for (int ti = 0; ti < 4; ++ti)
#pragma unroll
            for (int kb = 0; kb < 8; ++kb)
                acc[ti] = __builtin_amdgcn_mfma_f32_16x16x32_bf16(a[kb], bfr[ti][kb], acc[ti], 0, 0, 0);

#pragma unroll
        for (int ti = 0; ti < 4; ++ti) {
            int c = (wave * 4 + ti) * 16 + lm;
#pragma unroll
            for (int r = 0; r < 4; ++r) {
                int off = (m0 + p * 16 + q * 4 + r) * C_DIM + c;
                out[off] = acc[ti][r] + bv[ti] + feats[off];
            }
        }
    }
}

// ---------------------------------------------------------------- launch
extern "C" void kernel_launch(void* const* d_in, const int* in_sizes, int n_in,
                              void* d_out, int out_size, void* d_ws, size_t ws_size,
                              hipStream_t stream) {
    const float* coords = (const float*)d_in[0];
    const float* feats  = (const float*)d_in[1];
    const float* theta_w = (const float*)d_in[2];
    const float* theta_b = (const float*)d_in[3];
    const float* phi_w   = (const float*)d_in[4];
    const float* phi_b   = (const float*)d_in[5];
    const float* g_w     = (const float*)d_in[6];
    const float* g_b     = (const float*)d_in[7];
    const float* pe1_w1  = (const float*)d_in[8];
    const float* pe1_b1  = (const float*)d_in[9];
    const float* pe1_w2  = (const float*)d_in[10];
    const float* pe1_b2  = (const float*)d_in[11];
    const float* W_w     = (const float*)d_in[12];
    const float* W_b     = (const float*)d_in[13];
    float* out = (float*)d_out;

    char* w = (char*)d_ws;
    size_t off = 0;
    int* idx = (int*)(w + off);        off += (size_t)N_PTS * K_NN * 4;       // 512 KB
    bf16_t* fb = (bf16_t*)(w + off);   off += (size_t)N_PTS * C_DIM * 2;      // 4 MB
    bf16_t* wt = (bf16_t*)(w + off);   off += (size_t)5 * C_DIM * C_DIM * 2;  // 640 KB
    float* T = (float*)(w + off);      off += (size_t)N_PTS * C_DIM * 4;      // 8 MB
    bf16_t* Pb = (bf16_t*)(w + off);   off += (size_t)N_PTS * C_DIM * 2;      // 4 MB
    bf16_t* Gb = (bf16_t*)(w + off);   off += (size_t)N_PTS * C_DIM * 2;      // 4 MB
    bf16_t* yb = (bf16_t*)(w + off);   off += (size_t)N_PTS * C_DIM * 2;      // 4 MB
    (void)ws_size; (void)in_sizes; (void)n_in; (void)out_size;

    cast_feats_kernel<<<(N_PTS * C_DIM) / 1024, 256, 0, stream>>>(feats, fb);
    prep_weights_kernel<<<dim3(64, 5), 256, 0, stream>>>(theta_w, phi_w, g_w, pe1_w2, W_w, wt);
    knn_kernel<<<N_PTS / Q_BLK, 256, 0, stream>>>(coords, idx);
    proj_kernel<<<dim3(N_PTS / 64, 3), 256, 0, stream>>>(fb, wt, theta_b, phi_b, g_b, T, Pb, Gb);
    pe2_fused_kernel<<<N_PTS / P_BLK, 256, 0, stream>>>(coords, idx, T, Pb, Gb,
                                                        pe1_w1, pe1_b1, pe1_b2,
                                                        wt + 3 * C_DIM * C_DIM, yb);
    final_kernel<<<N_PTS / 64, 256, 0, stream>>>(yb, wt + 4 * C_DIM * C_DIM, W_b, feats, out);
}

// Round 9
// 272.527 us; speedup vs baseline: 1.2575x; 1.2575x over previous
//
#include <hip/hip_runtime.h>

typedef __bf16 bf16_t;
typedef bf16_t bf16x8 __attribute__((ext_vector_type(8)));
typedef bf16_t bf16x4 __attribute__((ext_vector_type(4)));
typedef float f32x4 __attribute__((ext_vector_type(4)));

#define N_PTS 8192
#define C_DIM 256
#define K_NN 16
#define Q_BLK 8  // queries per knn block: Q=4 -> 90us (occ-limited amortization), Q=16 -> 167us (VGPR/LDS occupancy cliff)

// ---------------------------------------------------------------- prep: cast feats to bf16
__global__ __launch_bounds__(256) void cast_feats_kernel(const float* __restrict__ f,
                                                         bf16_t* __restrict__ fb) {
    int i = (blockIdx.x * 256 + threadIdx.x) * 4;
    float4 v = *(const float4*)(f + i);
    bf16x4 o;
    o[0] = (bf16_t)v.x; o[1] = (bf16_t)v.y; o[2] = (bf16_t)v.z; o[3] = (bf16_t)v.w;
    *(bf16x4*)(fb + i) = o;
}

// ---------------------------------------------------------------- prep: weights -> MFMA B-fragment-major bf16
// Wt[((t*8+kb)*512) + lm*32 + q*8 + e] = W[k = kb*32+q*8+e][n = t*16+lm].
__global__ __launch_bounds__(256) void prep_weights_kernel(
    const float* __restrict__ w0, const float* __restrict__ w1,
    const float* __restrict__ w2, const float* __restrict__ w3,
    const float* __restrict__ w4, bf16_t* __restrict__ wt_base) {
    int m = blockIdx.y;
    const float* src = (m == 0) ? w0 : (m == 1) ? w1 : (m == 2) ? w2 : (m == 3) ? w3 : w4;
    bf16_t* dst = wt_base + m * (C_DIM * C_DIM);
#pragma unroll
    for (int i = 0; i < 4; ++i) {
        int o = blockIdx.x * 1024 + i * 256 + threadIdx.x;
        int tkb = o >> 9;           // t*8 + kb
        int rem = o & 511;
        int lm = rem >> 5;
        int r = rem & 31;           // q*8 + e
        int k = (tkb & 7) * 32 + r;
        int n = (tkb >> 3) * 16 + lm;
        dst[o] = (bf16_t)src[k * C_DIM + n];
    }
}

// ---------------------------------------------------------------- KNN: 8 queries per 256-thread block
// d2 bits emulate the numpy reference exactly (validated rounds 3-8):
//   sq  = (fl(x^2)+fl(y^2))+fl(z^2); dot = fma(z,z',fma(y,y',fl(x*x')));
//   d2  = fl(fl(sq_i+sq_j) - fl(2*dot))
// One coord stream serves 8 queries. Pass 1: per-thread mins -> 16 disjoint
// group-mins (512 pts each) -> tau[q] >= 16th-NN dist (provable). Pass 2: reload
// (L1-hot), recompute identical d2 bits, compact survivors per query. Selection:
// wave w handles queries 2w, 2w+1 via 16 wave-argmin rounds over unique
// (ordered_d2, idx) u64 keys. Ties -> lower index (stable top_k).
__global__ __launch_bounds__(256) void knn_kernel(const float* __restrict__ coords,
                                                  int* __restrict__ idx_out) {
    const int tid = threadIdx.x;
    const int wave = tid >> 6, lane = tid & 63;
    const int n0 = blockIdx.x * Q_BLK;
    __shared__ float red16[Q_BLK][16];
    __shared__ unsigned long long cand[Q_BLK][256];
    __shared__ int cnt[Q_BLK];

    if (tid < Q_BLK) cnt[tid] = 0;

    // load 8 query coords (24 floats, broadcast across lanes)
    float qx[Q_BLK], qy[Q_BLK], qz[Q_BLK], sqi[Q_BLK];
    {
        float qbuf[24];
#pragma unroll
        for (int v = 0; v < 6; ++v)
            *(float4*)(qbuf + v * 4) = *(const float4*)(coords + n0 * 3 + v * 4);
#pragma unroll
        for (int q = 0; q < Q_BLK; ++q) {
            qx[q] = qbuf[3 * q + 0]; qy[q] = qbuf[3 * q + 1]; qz[q] = qbuf[3 * q + 2];
            sqi[q] = __fadd_rn(__fadd_rn(__fmul_rn(qx[q], qx[q]), __fmul_rn(qy[q], qy[q])),
                               __fmul_rn(qz[q], qz[q]));
        }
    }

    const float INF = __int_as_float(0x7f800000);
    const float* cp = coords + tid * 96;

    // ---- pass 1: per-thread min per query over owned 32 points
    float lmin[Q_BLK];
#pragma unroll
    for (int q = 0; q < Q_BLK; ++q) lmin[q] = INF;
#pragma unroll
    for (int c = 0; c < 4; ++c) {
        float buf[24];
#pragma unroll
        for (int v = 0; v < 6; ++v)
            *(float4*)(buf + v * 4) = *(const float4*)(cp + c * 24 + v * 4);
#pragma unroll
        for (int p = 0; p < 8; ++p) {
            float x = buf[3 * p + 0], y = buf[3 * p + 1], z = buf[3 * p + 2];
            float sqj = __fadd_rn(__fadd_rn(__fmul_rn(x, x), __fmul_rn(y, y)),
                                  __fmul_rn(z, z));
#pragma unroll
            for (int q = 0; q < Q_BLK; ++q) {
                float dot = __fmaf_rn(z, qz[q], __fmaf_rn(y, qy[q], __fmul_rn(x, qx[q])));
                float d2 = __fsub_rn(__fadd_rn(sqi[q], sqj), __fmul_rn(2.0f, dot));
                lmin[q] = fminf(lmin[q], d2);
            }
        }
    }

    // ---- 16 disjoint group-mins (16 threads = 512 points each) -> tau per query
#pragma unroll
    for (int q = 0; q < Q_BLK; ++q) {
        float g = lmin[q];
        g = fminf(g, __shfl_xor(g, 1));
        g = fminf(g, __shfl_xor(g, 2));
        g = fminf(g, __shfl_xor(g, 4));
        g = fminf(g, __shfl_xor(g, 8));
        if ((lane & 15) == 0) red16[q][wave * 4 + (lane >> 4)] = g;
    }
    __syncthreads();

    float tau[Q_BLK];
#pragma unroll
    for (int q = 0; q < Q_BLK; ++q) {
        float t = red16[q][0];
#pragma unroll
        for (int i = 1; i < 16; ++i) t = fmaxf(t, red16[q][i]);
        tau[q] = t;
    }

    // ---- pass 2: reload (L1-hot), recompute identical d2 bits, compact survivors
#pragma unroll
    for (int c = 0; c < 4; ++c) {
        float buf[24];
#pragma unroll
        for (int v = 0; v < 6; ++v)
            *(float4*)(buf + v * 4) = *(const float4*)(cp + c * 24 + v * 4);
#pragma unroll
        for (int p = 0; p < 8; ++p) {
            float x = buf[3 * p + 0], y = buf[3 * p + 1], z = buf[3 * p + 2];
            float sqj = __fadd_rn(__fadd_rn(__fmul_rn(x, x), __fmul_rn(y, y)),
                                  __fmul_rn(z, z));
            int j = tid * 32 + c * 8 + p;
#pragma unroll
            for (int q = 0; q < Q_BLK; ++q) {
                float dot = __fmaf_rn(z, qz[q], __fmaf_rn(y, qy[q], __fmul_rn(x, qx[q])));
                float d2 = __fsub_rn(__fadd_rn(sqi[q], sqj), __fmul_rn(2.0f, dot));
                if (d2 <= tau[q]) {
                    unsigned u = __float_as_uint(d2);
                    u = (u & 0x80000000u) ? ~u : (u | 0x80000000u);
                    int slot = atomicAdd(&cnt[q], 1);
                    if (slot < 256)
                        cand[q][slot] = (((unsigned long long)u) << 32) | (unsigned)j;
                }
            }
        }
    }
    __syncthreads();

    // ---- selection: wave w -> queries 2w, 2w+1; 16 wave-argmin rounds each
#pragma unroll 1
    for (int i = 0; i < 2; ++i) {
        const int qq = wave * 2 + i;
        int m = cnt[qq]; if (m > 256) m = 256;
        unsigned long long k0 = ~0ull, k1 = ~0ull, k2 = ~0ull, k3 = ~0ull;
        if (lane < m) k0 = cand[qq][lane];
        if (lane + 64 < m) k1 = cand[qq][lane + 64];
        if (lane + 128 < m) k2 = cand[qq][lane + 128];
        if (lane + 192 < m) k3 = cand[qq][lane + 192];
        unsigned long long lm2 = k0; int li = 0;
        if (k1 < lm2) { lm2 = k1; li = 1; }
        if (k2 < lm2) { lm2 = k2; li = 2; }
        if (k3 < lm2) { lm2 = k3; li = 3; }
        int keep = 0;
#pragma unroll 1
        for (int r = 0; r < 16; ++r) {
            unsigned long long w = lm2;
#pragma unroll
            for (int off = 1; off < 64; off <<= 1) {
                unsigned long long o = __shfl_xor(w, off);
                w = (o < w) ? o : w;
            }
            if (lane == r) keep = (int)(unsigned)(w & 0xffffffffull);
            if (lm2 == w) {  // unique winner: retire slot, recompute local min
                if (li == 0) k0 = ~0ull;
                else if (li == 1) k1 = ~0ull;
                else if (li == 2) k2 = ~0ull;
                else k3 = ~0ull;
                lm2 = k0; li = 0;
                if (k1 < lm2) { lm2 = k1; li = 1; }
                if (k2 < lm2) { lm2 = k2; li = 2; }
                if (k3 < lm2) { lm2 = k3; li = 3; }
            }
        }
        if (lane < 16) idx_out[(n0 + qq) * K_NN + lane] = keep;
    }
}

// ---------------------------------------------------------------- proj: T/P/G = feats@{theta,phi,g}+b
// B-reuse split: wave owns 4 col-tiles (B preloaded in regs), loops 4 row-tiles.
__global__ __launch_bounds__(256, 2) void proj_kernel(
    const bf16_t* __restrict__ fb, const bf16_t* __restrict__ wt_base,
    const float* __restrict__ tb, const float* __restrict__ pb, const float* __restrict__ gb,
    float* __restrict__ T, bf16_t* __restrict__ Pb, bf16_t* __restrict__ Gb) {
    const int sel = blockIdx.y;
    const bf16_t* Wt = wt_base + sel * (C_DIM * C_DIM);
    const float* bias = (sel == 0) ? tb : (sel == 1) ? pb : gb;
    const int wave = threadIdx.x >> 6, lane = threadIdx.x & 63;
    const int q = lane >> 4, lm = lane & 15;
    const int m0 = blockIdx.x * 64;

    bf16x8 bfr[4][8];
#pragma unroll
    for (int ti = 0; ti < 4; ++ti)
#pragma unroll
        for (int kb = 0; kb < 8; ++kb)
            bfr[ti][kb] = *(const bf16x8*)(Wt + (((wave * 4 + ti) * 8 + kb) << 9) + lm * 32 + q * 8);

    float bv[4];
#pragma unroll
    for (int ti = 0; ti < 4; ++ti) bv[ti] = bias[(wave * 4 + ti) * 16 + lm];

#pragma unroll
    for (int p = 0; p < 4; ++p) {
        const bf16_t* arow = fb + (m0 + p * 16 + lm) * C_DIM + q * 8;
        bf16x8 a[8];
#pragma unroll
        for (int kb = 0; kb < 8; ++kb) a[kb] = *(const bf16x8*)(arow + kb * 32);
        f32x4 acc[4];
#pragma unroll
        for (int ti = 0; ti < 4; ++ti) acc[ti] = (f32x4){0.f, 0.f, 0.f, 0.f};
#pragma unroll
        for (int ti = 0; ti < 4; ++ti)
#pragma unroll
            for (int kb = 0; kb < 8; ++kb)
                acc[ti] = __builtin_amdgcn_mfma_f32_16x16x32_bf16(a[kb], bfr[ti][kb], acc[ti], 0, 0, 0);

#pragma unroll
        for (int ti = 0; ti < 4; ++ti) {
            int c = (wave * 4 + ti) * 16 + lm;
#pragma unroll
            for (int r = 0; r < 4; ++r) {
                float v = acc[ti][r] + bv[ti];
                int off = (m0 + p * 16 + q * 4 + r) * C_DIM + c;
                if (sel == 0) T[off] = v;
                else if (sel == 1) Pb[off] = (bf16_t)v;
                else Gb[off] = (bf16_t)v;
            }
        }
    }
}

// ---------------------------------------------------------------- pe1 + pe2 GEMM + softmax + weighted G-sum (fused)
#define HPAD 264  // 256 + 8 bf16 pad
#define P_BLK 8
#define HROWS (P_BLK * 16)
__global__ __launch_bounds__(256, 2) void pe2_fused_kernel(
    const float* __restrict__ coords, const int* __restrict__ idx,
    const float* __restrict__ T, const bf16_t* __restrict__ Pb, const bf16_t* __restrict__ Gb,
    const float* __restrict__ w1, const float* __restrict__ b1, const float* __restrict__ b2,
    const bf16_t* __restrict__ Wt2, bf16_t* __restrict__ yb) {
    __shared__ __align__(16) bf16_t h_lds[HROWS * HPAD];
    __shared__ float dxyz[HROWS][3];
    __shared__ int idxl[HROWS];
    const int tid = threadIdx.x;
    const int p0 = blockIdx.x * P_BLK;
    const int wave = tid >> 6, lane = tid & 63;
    const int q = lane >> 4, lm = lane & 15;

    bf16x8 bfr[4][8];
#pragma unroll
    for (int ti = 0; ti < 4; ++ti)
#pragma unroll
        for (int kb = 0; kb < 8; ++kb)
            bfr[ti][kb] = *(const bf16x8*)(Wt2 + (((wave * 4 + ti) * 8 + kb) << 9) + lm * 32 + q * 8);
    float b2c[4];
#pragma unroll
    for (int ti = 0; ti < 4; ++ti) b2c[ti] = b2[(wave * 4 + ti) * 16 + lm];

    if (tid < HROWS) {
        int n = p0 + (tid >> 4);
        int j = idx[n * K_NN + (tid & 15)];
        idxl[tid] = j;
        dxyz[tid][0] = coords[3 * j + 0] - coords[3 * n + 0];
        dxyz[tid][1] = coords[3 * j + 1] - coords[3 * n + 1];
        dxyz[tid][2] = coords[3 * j + 2] - coords[3 * n + 2];
    }
    __syncthreads();

    {   // pe1: h = relu(delta @ w1 + b1) -> LDS bf16 (thread owns col c = tid)
        int c = tid;
        float wx = w1[c], wy = w1[C_DIM + c], wz = w1[2 * C_DIM + c], bb = b1[c];
#pragma unroll 4
        for (int r = 0; r < HROWS; ++r) {
            float pre = dxyz[r][0] * wx + dxyz[r][1] * wy + dxyz[r][2] * wz + bb;
            h_lds[r * HPAD + c] = (bf16_t)fmaxf(pre, 0.0f);
        }
    }
    __syncthreads();

#pragma unroll 1
    for (int lp = 0; lp < P_BLK; ++lp) {
        const int n = p0 + lp;
        const bf16_t* hrow = h_lds + (lp * 16 + lm) * HPAD + q * 8;
        bf16x8 a[8];
#pragma unroll
        for (int kb = 0; kb < 8; ++kb) a[kb] = *(const bf16x8*)(hrow + kb * 32);
        f32x4 acc[4];
#pragma unroll
        for (int ti = 0; ti < 4; ++ti) acc[ti] = (f32x4){0.f, 0.f, 0.f, 0.f};
#pragma unroll
        for (int ti = 0; ti < 4; ++ti)
#pragma unroll
            for (int kb = 0; kb < 8; ++kb)
                acc[ti] = __builtin_amdgcn_mfma_f32_16x16x32_bf16(a[kb], bfr[ti][kb], acc[ti], 0, 0, 0);

        int jr[4];
#pragma unroll
        for (int r = 0; r < 4; ++r) jr[r] = idxl[lp * 16 + q * 4 + r];

#pragma unroll
        for (int ti = 0; ti < 4; ++ti) {
            int c = (wave * 4 + ti) * 16 + lm;
            float phi[4], gv[4];
#pragma unroll
            for (int r = 0; r < 4; ++r) {
                phi[r] = (float)Pb[jr[r] * C_DIM + c];
                gv[r]  = (float)Gb[jr[r] * C_DIM + c];
            }
            float Tn = T[n * C_DIM + c];
            float df[4];
#pragma unroll
            for (int r = 0; r < 4; ++r) {
                float pe = acc[ti][r] + b2c[ti];
                df[r] = (pe * (Tn - phi[r]) + pe) * 0.0625f;  // /sqrt(256)
            }
            float mx = fmaxf(fmaxf(df[0], df[1]), fmaxf(df[2], df[3]));
            mx = fmaxf(mx, __shfl_xor(mx, 16));
            mx = fmaxf(mx, __shfl_xor(mx, 32));
            float e[4], s = 0.f;
#pragma unroll
            for (int r = 0; r < 4; ++r) { e[r] = __expf(df[r] - mx); s += e[r]; }
            s += __shfl_xor(s, 16);
            s += __shfl_xor(s, 32);
            float inv = 1.0f / s;
            float y = 0.f;
#pragma unroll
            for (int r = 0; r < 4; ++r) y += e[r] * inv * gv[r];
            y += __shfl_xor(y, 16);
            y += __shfl_xor(y, 32);
            if (q == 0) yb[n * C_DIM + c] = (bf16_t)y;
        }
    }
}

// ---------------------------------------------------------------- final: out = y@W_w + W_b + feats
__global__ __launch_bounds__(256, 2) void final_kernel(
    const bf16_t* __restrict__ yb, const bf16_t* __restrict__ Wt,
    const float* __restrict__ Wb, const float* __restrict__ feats,
    float* __restrict__ out) {
    const int wave = threadIdx.x >> 6, lane = threadIdx.x & 63;
    const int q = lane >> 4, lm = lane & 15;
    const int m0 = blockIdx.x * 64;

    bf16x8 bfr[4][8];
#pragma unroll
    for (int ti = 0; ti < 4; ++ti)
#pragma unroll
        for (int kb = 0; kb < 8; ++kb)
            bfr[ti][kb] = *(const bf16x8*)(Wt + (((wave * 4 + ti) * 8 + kb) << 9) + lm * 32 + q * 8);
    float bv[4];
#pragma unroll
    for (int ti = 0; ti < 4; ++ti) bv[ti] = Wb[(wave * 4 + ti) * 16 + lm];

#pragma unroll
    for (int p = 0; p < 4; ++p) {
        const bf16_t* arow = yb + (m0 + p * 16 + lm) * C_DIM + q * 8;
        bf16x8 a[8];
#pragma unroll
        for (int kb = 0; kb < 8; ++kb) a[kb] = *(const bf16x8*)(arow + kb * 32);
        f32x4 acc[4];
#pragma unroll
        for (int ti = 0; ti < 4; ++ti) acc[ti] = (f32x4){0.f, 0.f, 0.f, 0.f};
#pragma unroll
        for (int ti = 0; ti < 4; ++ti)
#pragma unroll
            for (int kb = 0; kb < 8; ++kb)
                acc[ti] = __builtin_amdgcn_mfma_f32_16x16x32_bf16(a[kb], bfr[ti][kb], acc[ti], 0, 0, 0);

#pragma unroll
        for (int ti = 0; ti < 4; ++ti) {
            int c = (wave * 4 + ti) * 16 + lm;
#pragma unroll
            for (int r = 0; r < 4; ++r) {
                int off = (m0 + p * 16 + q * 4 + r) * C_DIM + c;
                out[off] = acc[ti][r] + bv[ti] + feats[off];
            }
        }
    }
}

// ---------------------------------------------------------------- launch
extern "C" void kernel_launch(void* const* d_in, const int* in_sizes, int n_in,
                              void* d_out, int out_size, void* d_ws, size_t ws_size,
                              hipStream_t stream) {
    const float* coords = (const float*)d_in[0];
    const float* feats  = (const float*)d_in[1];
    const float* theta_w = (const float*)d_in[2];
    const float* theta_b = (const float*)d_in[3];
    const float* phi_w   = (const float*)d_in[4];
    const float* phi_b   = (const float*)d_in[5];
    const float* g_w     = (const float*)d_in[6];
    const float* g_b     = (const float*)d_in[7];
    const float* pe1_w1  = (const float*)d_in[8];
    const float* pe1_b1  = (const float*)d_in[9];
    const float* pe1_w2  = (const float*)d_in[10];
    const float* pe1_b2  = (const float*)d_in[11];
    const float* W_w     = (const float*)d_in[12];
    const float* W_b     = (const float*)d_in[13];
    float* out = (float*)d_out;

    char* w = (char*)d_ws;
    size_t off = 0;
    int* idx = (int*)(w + off);        off += (size_t)N_PTS * K_NN * 4;       // 512 KB
    bf16_t* fb = (bf16_t*)(w + off);   off += (size_t)N_PTS * C_DIM * 2;      // 4 MB
    bf16_t* wt = (bf16_t*)(w + off);   off += (size_t)5 * C_DIM * C_DIM * 2;  // 640 KB
    float* T = (float*)(w + off);      off += (size_t)N_PTS * C_DIM * 4;      // 8 MB
    bf16_t* Pb = (bf16_t*)(w + off);   off += (size_t)N_PTS * C_DIM * 2;      // 4 MB
    bf16_t* Gb = (bf16_t*)(w + off);   off += (size_t)N_PTS * C_DIM * 2;      // 4 MB
    bf16_t* yb = (bf16_t*)(w + off);   off += (size_t)N_PTS * C_DIM * 2;      // 4 MB
    (void)ws_size; (void)in_sizes; (void)n_in; (void)out_size;

    cast_feats_kernel<<<(N_PTS * C_DIM) / 1024, 256, 0, stream>>>(feats, fb);
    prep_weights_kernel<<<dim3(64, 5), 256, 0, stream>>>(theta_w, phi_w, g_w, pe1_w2, W_w, wt);
    knn_kernel<<<N_PTS / Q_BLK, 256, 0, stream>>>(coords, idx);
    proj_kernel<<<dim3(N_PTS / 64, 3), 256, 0, stream>>>(fb, wt, theta_b, phi_b, g_b, T, Pb, Gb);
    pe2_fused_kernel<<<N_PTS / P_BLK, 256, 0, stream>>>(coords, idx, T, Pb, Gb,
                                                        pe1_w1, pe1_b1, pe1_b2,
                                                        wt + 3 * C_DIM * C_DIM, yb);
    final_kernel<<<N_PTS / 64, 256, 0, stream>>>(yb, wt + 4 * C_DIM * C_DIM, W_b, feats, out);
}